// Round 9
// baseline (257.927 us; speedup 1.0000x reference)
//
#include <hip/hip_runtime.h>

#define H 1024
#define QD 16
#define BATCH 4
#define SEQ 2048
#define MROWS 8192  // BATCH*SEQ
#define KCH 64      // fused_attn k-chunk
#define NT (SEQ / KCH)

typedef __bf16 bf16x8 __attribute__((ext_vector_type(8)));
typedef __bf16 bf16x4 __attribute__((ext_vector_type(4)));
typedef float f32x4 __attribute__((ext_vector_type(4)));
typedef float f32x16 __attribute__((ext_vector_type(16)));
typedef unsigned int u32;
typedef u32 u32x4 __attribute__((ext_vector_type(4)));

__device__ __forceinline__ void async_g2l_16(const void* g, void* l) {
  __builtin_amdgcn_global_load_lds(
      (const __attribute__((address_space(1))) unsigned int*)g,
      (__attribute__((address_space(3))) unsigned int*)l, 16, 0, 0);
}

__device__ __forceinline__ u32 cvt_pk_bf16(float a, float b) {
  u32 d;
  asm("v_cvt_pk_bf16_f32 %0, %1, %2" : "=v"(d) : "v"(a), "v"(b));
  return d;
}

// ---------------- fp32 -> bf16 hi/lo split (x) ----------------
__global__ __launch_bounds__(256) void cvt_split(const float* __restrict__ src,
                                                 __bf16* __restrict__ hi,
                                                 __bf16* __restrict__ lo, int n) {
  int i = (blockIdx.x * 256 + threadIdx.x) * 4;
  if (i < n) {
    float4 f = *(const float4*)(src + i);
    bf16x4 h, l;
    h[0] = (__bf16)f.x; l[0] = (__bf16)(f.x - (float)h[0]);
    h[1] = (__bf16)f.y; l[1] = (__bf16)(f.y - (float)h[1]);
    h[2] = (__bf16)f.z; l[2] = (__bf16)(f.z - (float)h[2]);
    h[3] = (__bf16)f.w; l[3] = (__bf16)(f.w - (float)h[3]);
    *(bf16x4*)(hi + i) = h;
    *(bf16x4*)(lo + i) = l;
  }
}

// ---------------- fp32 [R][C] -> bf16 transposed [C][R] ----------------
__global__ __launch_bounds__(256) void transpose_cvt_f32_bf16(
    const float* __restrict__ src, __bf16* __restrict__ dst, int R, int C) {
  __shared__ float t[32][33];
  const int rb = blockIdx.y * 32, cb = blockIdx.x * 32;
  const int c = threadIdx.x & 31;
  const int r0 = threadIdx.x >> 5;
#pragma unroll
  for (int rr = r0; rr < 32; rr += 8)
    t[rr][c] = src[(long)(rb + rr) * C + cb + c];
  __syncthreads();
#pragma unroll
  for (int rr = r0; rr < 32; rr += 8)
    dst[(long)(cb + rr) * R + rb + c] = (__bf16)t[c][rr];
}

// ---------------- CqkT (Bt layout [32][1024]) in bf16 hi/lo ----------------
__global__ __launch_bounds__(256) void k2_cqk(const float* __restrict__ Wq,
                                              const float* __restrict__ Wk,
                                              const float* __restrict__ We,
                                              __bf16* __restrict__ Cth,
                                              __bf16* __restrict__ Ctl) {
  const int gw = blockIdx.x * 4 + (threadIdx.x >> 6);  // 0..2047
  const int lane = threadIdx.x & 63;
  const int mat = gw & 1, k = gw >> 1;
  const float* Wrow = (mat ? Wk : Wq) + (long)k * H;
  const int col = lane & 15, q4 = lane >> 4;
  const float* wp = Wrow + q4 * 256;
  const float* wep = We + (long)q4 * 256 * QD + col;
  float acc = 0.f;
#pragma unroll 4
  for (int n0 = 0; n0 < 256; n0 += 4) {
    float4 w4 = *(const float4*)(wp + n0);
    acc += w4.x * wep[(n0 + 0) * QD];
    acc += w4.y * wep[(n0 + 1) * QD];
    acc += w4.z * wep[(n0 + 2) * QD];
    acc += w4.w * wep[(n0 + 3) * QD];
  }
  acc += __shfl_xor(acc, 16);
  acc += __shfl_xor(acc, 32);
  if (lane < 16) {
    __bf16 hi = (__bf16)acc;
    __bf16 lo = (__bf16)(acc - (float)hi);
    long idx = (long)(mat * 16 + col) * H + k;
    Cth[idx] = hi;
    Ctl[idx] = lo;
  }
}

// ---------------- dvec[j] = (bq|bk)@We + be (parallel v2) ----------------
__global__ __launch_bounds__(512) void k2b_dvec(
    const float* __restrict__ bq, const float* __restrict__ bk,
    const float* __restrict__ We, const float* __restrict__ be,
    float* __restrict__ dvec) {
  __shared__ float part[16][32];
  const int tid = threadIdx.x;  // 512
  const int j = tid & 31, p = tid >> 5;  // p 0..15
  const int mat = j >> 4, col = j & 15;
  const float* b = mat ? bk : bq;
  float acc = 0.f;
  for (int n = p * 64; n < p * 64 + 64; ++n) acc += b[n] * We[n * QD + col];
  part[p][j] = acc;
  __syncthreads();
  if (tid < 32) {
    float sum = be[tid & 15];
    for (int p2 = 0; p2 < 16; ++p2) sum += part[p2][tid];
    dvec[tid] = sum;
  }
}

// ---------------- embed via MFMA (hi/lo split), fused normalize ----------------
// v3: outputs UNPADDED bf16 [S][16]; qq carries sqrt(log2 e).
__global__ __launch_bounds__(1024) void k3_embed_mfma(
    const __bf16* __restrict__ xh, const __bf16* __restrict__ xl,
    const __bf16* __restrict__ Cth, const __bf16* __restrict__ Ctl,
    const float* __restrict__ dvec, __bf16* __restrict__ qq16,
    __bf16* __restrict__ kk16) {
  __shared__ __bf16 Ah[4][32 * 64];
  __shared__ __bf16 Al[4][32 * 64];
  __shared__ __bf16 Bh[4][32 * 64];
  __shared__ __bf16 Bl[4][32 * 64];
  const int tid = threadIdx.x;
  const int lane = tid & 63;
  const int w = tid >> 6;       // 0..15
  const int kb = w >> 2;        // K quarter this wave computes on
  const int w4 = w & 3;
  const int rowhalf = w4 >> 1;  // 0/1 -> rows 0-15 / 16-31
  const int ntile = w4 & 1;     // 0 -> qq, 1 -> kk
  const int l15 = lane & 15, quad = lane >> 4;
  const long rowBase = (long)blockIdx.x * 32;

  const int half = tid >> 8;       // 0..3
  const int tl = tid & 255;
  const int srow = tl >> 3;        // 0..31
  const int seg = tl & 7;
  const int segsw = (seg ^ (srow & 7)) * 8;
  const long gk = half * 256 + segsw;
  const __bf16* agh = xh + (rowBase + srow) * H + gk;
  const __bf16* agl = xl + (rowBase + srow) * H + gk;
  const __bf16* bgh = Cth + (long)srow * H + gk;
  const __bf16* bgl = Ctl + (long)srow * H + gk;
  __bf16* lah = &Ah[half][srow * 64 + seg * 8];
  __bf16* lal = &Al[half][srow * 64 + seg * 8];
  __bf16* lbh = &Bh[half][srow * 64 + seg * 8];
  __bf16* lbl = &Bl[half][srow * 64 + seg * 8];

  f32x4 acc;
  acc[0] = 0.f; acc[1] = 0.f; acc[2] = 0.f; acc[3] = 0.f;
  const int arow = (rowhalf * 16 + l15) * 64;
  const int brow = (ntile * 16 + l15) * 64;
  const int h7 = l15 & 7;

  for (int k0 = 0; k0 < 256; k0 += 64) {
    async_g2l_16(agh + k0, lah);
    async_g2l_16(agl + k0, lal);
    async_g2l_16(bgh + k0, lbh);
    async_g2l_16(bgl + k0, lbl);
    __syncthreads();
#pragma unroll
    for (int s = 0; s < 2; ++s) {
      const int slot = ((s * 4 + quad) ^ h7) * 8;
      bf16x8 fah = *(const bf16x8*)&Ah[kb][arow + slot];
      bf16x8 fal = *(const bf16x8*)&Al[kb][arow + slot];
      bf16x8 fbh = *(const bf16x8*)&Bh[kb][brow + slot];
      bf16x8 fbl = *(const bf16x8*)&Bl[kb][brow + slot];
      acc = __builtin_amdgcn_mfma_f32_16x16x32_bf16(fah, fbh, acc, 0, 0, 0);
      acc = __builtin_amdgcn_mfma_f32_16x16x32_bf16(fal, fbh, acc, 0, 0, 0);
      acc = __builtin_amdgcn_mfma_f32_16x16x32_bf16(fah, fbl, acc, 0, 0, 0);
    }
    __syncthreads();
  }

  if (kb > 0) ((f32x4*)&Ah[kb][0])[w4 * 64 + lane] = acc;
  __syncthreads();
  if (kb == 0) {
#pragma unroll
    for (int q = 1; q < 4; ++q) {
      f32x4 o = ((const f32x4*)&Ah[q][0])[w4 * 64 + lane];
      acc[0] += o[0]; acc[1] += o[1]; acc[2] += o[2]; acc[3] += o[3];
    }
    const float dv = dvec[ntile * 16 + l15];
    const float osc = ntile ? 1.0f : 1.20112240878f;  // sqrt(log2 e) into qq
    __bf16* outp = ntile ? kk16 : qq16;
#pragma unroll
    for (int r = 0; r < 4; ++r) {
      float z = acc[r] + dv;
      float s2 = z * z;
      s2 += __shfl_xor(s2, 1);
      s2 += __shfl_xor(s2, 2);
      s2 += __shfl_xor(s2, 4);
      s2 += __shfl_xor(s2, 8);
      float val = z * rsqrtf(s2 + 1e-8f) * osc;
      long row = rowBase + rowhalf * 16 + quad * 4 + r;
      outp[row * QD + l15] = (__bf16)val;
    }
  }
}

// ---------------- fused attention v4: 32x32 MFMA, in-register P ----------------
// 8 waves, 128q x 256h, KCH=64, V DOUBLE-buffered (2x32KB, stage after barrier).
// S: mfma_32x32x16 (K=16=QD exactly, no zero-pad) -> P lane-local in q
// (col=lane&31). PV B-frags built IN REGISTERS via cvt_pk + shfl_xor(.,32)
// (lo lane holds k{0-3,8-11,...}, hi +4; exchange across half-wave).
// NO Plds, NO lgkmcnt drain, NO rsum LDS (rowsum = end shfl_xor 32).
// Waves: wq=w&3 (32q tile), wh=w>>2 (128h half; S 2x redundant, cheap).
// Buffer safety: stage(t+1)->buf[(t+1)&1] issued after barrier(t); all waves
// passed barrier(t) => PV(t-1) reads of that buffer complete. kk loads issued
// BEFORE the stage so S's implicit wait doesn't drain the stage; vmcnt(0)
// before next barrier (stage had all of PV+S to land, L2-resident).
__global__ __launch_bounds__(512, 2) void fused_attn(
    const __bf16* __restrict__ qq16, const __bf16* __restrict__ kk16,
    const __bf16* __restrict__ v_t, __bf16* __restrict__ attn) {
  __shared__ __bf16 Vlds[2][256 * KCH];  // 64KB
  const int tid = threadIdx.x;
  const int lane = tid & 63;
  const int w = tid >> 6;   // 0..7
  const int l31 = lane & 31;
  const int lh = lane >> 5; // half-wave
  const int wq = w & 3;     // q-tile (32q)
  const int wh = w >> 2;    // h-half (128h)

  // XCD-aware remap: 256 blocks, 16 (b,h) panels -> 2 panels/XCD.
  const int bid = blockIdx.x;
  const int xcd = bid & 7, s = bid >> 3;
  const int panel = xcd * 2 + (s >> 4);
  const int b = panel >> 2;
  const long hbase = (long)(panel & 3) * 256;
  const long qbase = (long)(s & 15) * 128;

  // qq B-frag (loop-invariant): B[j=q=l31][d=lh*8+e]
  const bf16x8 qqf = *(const bf16x8*)(
      qq16 + ((long)b * SEQ + qbase + wq * 32 + l31) * QD + lh * 8);
  const __bf16* kkB = kk16 + ((long)b * SEQ + l31) * QD + lh * 8;

  // V staging: 4 g2l/thread, rows vR+{0,64,128,192}, pre-swizzled source.
  const int vR = tid >> 3;
  const int vSL = (tid & 7) ^ (vR & 7);
  const __bf16* vg = v_t + (long)b * H * SEQ + (hbase + vR) * SEQ + vSL * 8;
  const int vD = vR * KCH + (tid & 7) * 8;  // lane-linear LDS dest (elems)

  // V read offsets: A[i=h=l31][kc=lh*8+e], row=wh*128+ht*32+l31, g=kf*2+lh
  int vOff[4][4];
#pragma unroll
  for (int ht = 0; ht < 4; ++ht) {
    const int row = wh * 128 + ht * 32 + l31;
#pragma unroll
    for (int kf = 0; kf < 4; ++kf)
      vOff[ht][kf] = row * KCH + (((kf * 2 + lh) ^ (row & 7)) << 3);
  }

  f32x16 acc[4];
#pragma unroll
  for (int ht = 0; ht < 4; ++ht)
#pragma unroll
    for (int r = 0; r < 16; ++r) acc[ht][r] = 0.f;
  float rs = 0.f;
  bf16x8 kkf[2];
  u32 pfw[4][4];  // 4 B-frags x 4 dwords, all statically indexed

#define S_TILE(KT)                                                            \
  {                                                                           \
    f32x16 sv;                                                                \
    _Pragma("unroll") for (int r = 0; r < 16; ++r) sv[r] = 0.f;               \
    sv = __builtin_amdgcn_mfma_f32_32x32x16_bf16(kkf[KT], qqf, sv, 0, 0, 0);  \
    float p[16];                                                              \
    _Pragma("unroll") for (int r = 0; r < 16; ++r) {                          \
      p[r] = exp2f(sv[r] * sv[r]);                                            \
      rs += p[r];                                                             \
    }                                                                         \
    u32 d0 = cvt_pk_bf16(p[0], p[1]), d1 = cvt_pk_bf16(p[2], p[3]);           \
    u32 d2 = cvt_pk_bf16(p[4], p[5]), d3 = cvt_pk_bf16(p[6], p[7]);           \
    u32 d4 = cvt_pk_bf16(p[8], p[9]), d5 = cvt_pk_bf16(p[10], p[11]);         \
    u32 d6 = cvt_pk_bf16(p[12], p[13]), d7 = cvt_pk_bf16(p[14], p[15]);       \
    u32 x2 = __shfl_xor(d2, 32), x0 = __shfl_xor(d0, 32);                     \
    u32 x3 = __shfl_xor(d3, 32), x1 = __shfl_xor(d1, 32);                     \
    pfw[(KT)*2][0] = lh ? x2 : d0;                                            \
    pfw[(KT)*2][1] = lh ? x3 : d1;                                            \
    pfw[(KT)*2][2] = lh ? d2 : x0;                                            \
    pfw[(KT)*2][3] = lh ? d3 : x1;                                            \
    u32 x6 = __shfl_xor(d6, 32), x4 = __shfl_xor(d4, 32);                     \
    u32 x7 = __shfl_xor(d7, 32), x5 = __shfl_xor(d5, 32);                     \
    pfw[(KT)*2 + 1][0] = lh ? x6 : d4;                                        \
    pfw[(KT)*2 + 1][1] = lh ? x7 : d5;                                        \
    pfw[(KT)*2 + 1][2] = lh ? d6 : x4;                                        \
    pfw[(KT)*2 + 1][3] = lh ? d7 : x5;                                        \
  }

#define PV_CHUNK(VRP)                                                         \
  {                                                                           \
    const __bf16* Vr = (VRP);                                                 \
    _Pragma("unroll") for (int kf = 0; kf < 4; ++kf) {                        \
      u32x4 pw = {pfw[kf][0], pfw[kf][1], pfw[kf][2], pfw[kf][3]};            \
      bf16x8 pfr = *(bf16x8*)&pw;                                             \
      _Pragma("unroll") for (int ht = 0; ht < 4; ++ht) {                      \
        bf16x8 av = *(const bf16x8*)&Vr[vOff[ht][kf]];                        \
        acc[ht] = __builtin_amdgcn_mfma_f32_32x32x16_bf16(av, pfr, acc[ht],   \
                                                          0, 0, 0);           \
      }                                                                       \
    }                                                                         \
  }

#define STAGE(BUF, KN)                                                        \
  _Pragma("unroll") for (int m = 0; m < 4; ++m)                               \
      async_g2l_16(vg + (KN) + (long)m * 64 * SEQ,                            \
                   &Vlds[BUF][vD + m * 64 * KCH]);

  // prologue: stage(0)->buf0; kk(0); S(0) in regs; drain
  STAGE(0, 0);
  kkf[0] = *(const bf16x8*)(kkB);
  kkf[1] = *(const bf16x8*)(kkB + 32 * QD);
  S_TILE(0);
  S_TILE(1);
  asm volatile("s_waitcnt vmcnt(0)" ::: "memory");

  for (int t = 0; t < NT - 1; ++t) {
    __builtin_amdgcn_s_barrier();
    const long kn = (long)(t + 1) * KCH;
    kkf[0] = *(const bf16x8*)(kkB + kn * QD);          // kk first (vmcnt order)
    kkf[1] = *(const bf16x8*)(kkB + (kn + 32) * QD);
    STAGE((t + 1) & 1, kn);
    PV_CHUNK(Vlds[t & 1]);   // uses P(t) before S overwrites
    S_TILE(0);               // P(t+1)
    S_TILE(1);
    asm volatile("s_waitcnt vmcnt(0)" ::: "memory");
    __builtin_amdgcn_sched_barrier(0);
  }
  __builtin_amdgcn_s_barrier();
  PV_CHUNK(Vlds[(NT - 1) & 1]);

#undef STAGE
#undef PV_CHUNK
#undef S_TILE

  // rowsum: lane holds half the k's for its q row; partner has the rest.
  const float rtot = rs + __shfl_xor(rs, 32);
  const float rinv = 1.0f / rtot;

  __bf16* ob = attn + ((long)b * SEQ + qbase + wq * 32 + l31) * H + hbase +
               wh * 128;
#pragma unroll
  for (int ht = 0; ht < 4; ++ht)
#pragma unroll
    for (int g = 0; g < 4; ++g) {
      bf16x4 pv;
#pragma unroll
      for (int e = 0; e < 4; ++e) pv[e] = (__bf16)(acc[ht][g * 4 + e] * rinv);
      *(bf16x4*)&ob[ht * 32 + g * 8 + lh * 4] = pv;
    }
}

// ---------------- m97-style GEMM + XOR-swizzled LDS: C = A @ Bt^T (+bias) ----
// v2: XCD-aware block remap (T1); grid must be (8, 64).
template <int OUTMODE, int HASBIAS>
__global__ __launch_bounds__(256) void gemm_bt(
    const __bf16* __restrict__ A, const __bf16* __restrict__ Bt,
    void* __restrict__ Cout, const float* __restrict__ bias, int M, int N, int K) {
  __shared__ __bf16 Alds[128 * 64];
  __shared__ __bf16 Blds[128 * 64];
  const int tid = threadIdx.x;
  const int lane = tid & 63;
  const int w = tid >> 6;
  const int wm = w >> 1, wn = w & 1;
  const int l15 = lane & 15, quad = lane >> 4;

  const int flat = blockIdx.y * 8 + blockIdx.x;  // 0..511
  const int xcd = flat & 7, idx = flat >> 3;
  const int rowPanel = xcd * 8 + (idx >> 3);
  const int colBlk = idx & 7;
  const long rowBase = (long)rowPanel * 128;
  const long colBase = (long)colBlk * 128;

  const int srow = lane >> 3;
  const int segsw = ((lane & 7) ^ srow) * 8;

  const __bf16* ag[4];
  const __bf16* bg[4];
  __bf16* as_[4];
  __bf16* bs_[4];
#pragma unroll
  for (int j = 0; j < 4; ++j) {
    int r = j * 32 + w * 8;
    ag[j] = A + (rowBase + r + srow) * (long)K + segsw;
    bg[j] = Bt + (colBase + r + srow) * (long)K + segsw;
    as_[j] = &Alds[r * 64 + (lane & 7) * 8];
    bs_[j] = &Blds[r * 64 + (lane & 7) * 8];
  }

  f32x4 acc[4][4];
#pragma unroll
  for (int i = 0; i < 4; ++i)
#pragma unroll
    for (int j = 0; j < 4; ++j) {
      acc[i][j][0] = 0.f; acc[i][j][1] = 0.f; acc[i][j][2] = 0.f; acc[i][j][3] = 0.f;
    }

  const int h7 = l15 & 7;

  for (int k0 = 0; k0 < K; k0 += 64) {
#pragma unroll
    for (int j = 0; j < 4; ++j) {
      async_g2l_16(ag[j], as_[j]);
      async_g2l_16(bg[j], bs_[j]);
      ag[j] += 64;
      bg[j] += 64;
    }
    __syncthreads();
#pragma unroll
    for (int s = 0; s < 2; ++s) {
      const int slot = ((s * 4 + quad) ^ h7) * 8;
      bf16x8 af[4], bfv[4];
#pragma unroll
      for (int i = 0; i < 4; ++i) {
        af[i] = *(const bf16x8*)&Alds[(wm * 64 + i * 16 + l15) * 64 + slot];
        bfv[i] = *(const bf16x8*)&Blds[(wn * 64 + i * 16 + l15) * 64 + slot];
      }
#pragma unroll
      for (int i = 0; i < 4; ++i)
#pragma unroll
        for (int j = 0; j < 4; ++j)
          acc[i][j] =
              __builtin_amdgcn_mfma_f32_16x16x32_bf16(af[i], bfv[j], acc[i][j], 0, 0, 0);
    }
    __syncthreads();
  }

  const long crow0 = rowBase + wm * 64 + quad * 4;
  const long ccol0 = colBase + wn * 64 + l15;
#pragma unroll
  for (int i = 0; i < 4; ++i) {
#pragma unroll
    for (int j = 0; j < 4; ++j) {
      long col = ccol0 + j * 16;
      float bb = HASBIAS ? bias[col] : 0.f;
      if (OUTMODE == 2) {
        long row0 = crow0 + i * 16;
        int bz = (int)(row0 >> 11);
        long rb = row0 & (SEQ - 1);
        bf16x4 pv;
#pragma unroll
        for (int r = 0; r < 4; ++r) pv[r] = (__bf16)(acc[i][j][r] + bb);
        *(bf16x4*)&((__bf16*)Cout)[((long)bz * N + col) * SEQ + rb] = pv;
      } else {
#pragma unroll
        for (int r = 0; r < 4; ++r) {
          long row = crow0 + i * 16 + r;
          float val = acc[i][j][r] + bb;
          if (OUTMODE == 0)
            ((float*)Cout)[row * N + col] = val;
          else
            ((__bf16*)Cout)[row * N + col] = (__bf16)val;
        }
      }
    }
  }
}

extern "C" void kernel_launch(void* const* d_in, const int* in_sizes, int n_in,
                              void* d_out, int out_size, void* d_ws, size_t ws_size,
                              hipStream_t stream) {
  const float* x = (const float*)d_in[0];
  const float* Wq = (const float*)d_in[1];
  const float* bq = (const float*)d_in[2];
  const float* Wk = (const float*)d_in[3];
  const float* bk = (const float*)d_in[4];
  const float* Wv = (const float*)d_in[5];
  const float* bv = (const float*)d_in[6];
  const float* We = (const float*)d_in[7];
  const float* be = (const float*)d_in[8];
  const float* Wo = (const float*)d_in[9];
  const float* bo = (const float*)d_in[10];
  float* out = (float*)d_out;

  char* ws = (char*)d_ws;
  size_t o = 0;
  auto alloc = [&](size_t n) {
    size_t r = o;
    o += (n + 255) & ~(size_t)255;
    return r;
  };
  __bf16* xbf = (__bf16*)(ws + alloc((size_t)MROWS * H * 2));  // x hi
  __bf16* v_t = (__bf16*)(ws + alloc((size_t)MROWS * H * 2));  // v^T [B][H][S]
  __bf16* attn = (__bf16*)(ws + alloc((size_t)MROWS * H * 2));
  __bf16* Wvt = (__bf16*)(ws + alloc((size_t)H * H * 2));
  __bf16* Wot = (__bf16*)(ws + alloc((size_t)H * H * 2));
  __bf16* Cth = (__bf16*)(ws + alloc((size_t)32 * H * 2));
  __bf16* Ctl = (__bf16*)(ws + alloc((size_t)32 * H * 2));
  float* dvec = (float*)(ws + alloc(32 * 4));
  __bf16* qq16 = (__bf16*)(ws + alloc((size_t)MROWS * QD * 2));
  __bf16* kk16 = (__bf16*)(ws + alloc((size_t)MROWS * QD * 2));
  // Alias (stream-ordered lifetime separation):
  __bf16* xlo = attn;  // x lo part: dead before attn is written (fused_attn)
  if (ws_size < o) return;

  // 1) x -> bf16 hi/lo split
  cvt_split<<<MROWS * H / 1024, 256, 0, stream>>>(x, xbf, xlo, MROWS * H);
  // 2) Wv^T, Wo^T as bf16
  transpose_cvt_f32_bf16<<<dim3(32, 32), 256, 0, stream>>>(Wv, Wvt, H, H);
  transpose_cvt_f32_bf16<<<dim3(32, 32), 256, 0, stream>>>(Wo, Wot, H, H);
  // 3) collapsed embed matrices (bf16 hi/lo, Bt layout) + bias fold
  k2_cqk<<<512, 256, 0, stream>>>(Wq, Wk, We, Cth, Ctl);
  k2b_dvec<<<1, 512, 0, stream>>>(bq, bk, We, be, dvec);
  // 4) unit-norm quantum embeds via MFMA -> bf16 [S][16] unpadded
  k3_embed_mfma<<<MROWS / 32, 1024, 0, stream>>>(xbf, xlo, Cth, Ctl, dvec, qq16, kk16);
  // 5) v = x@Wv + bv, written TRANSPOSED per batch -> v_t[b][h][s]
  gemm_bt<2, 1><<<dim3(8, 64), 256, 0, stream>>>(xbf, Wvt, v_t, bv, MROWS, H, H);
  // 6) fused attn v4: 32x32 MFMA, in-register P, no Plds
  fused_attn<<<256, 512, 0, stream>>>(qq16, kk16, v_t, attn);
  // 7) out = attended @ Wo + bo  (fp32 out)
  gemm_bt<0, 1><<<dim3(8, 64), 256, 0, stream>>>(attn, Wot, out, bo, MROWS, H, H);
}

// Round 10
// 240.125 us; speedup vs baseline: 1.0741x; 1.0741x over previous
//
#include <hip/hip_runtime.h>

#define H 1024
#define QD 16
#define BATCH 4
#define SEQ 2048
#define MROWS 8192  // BATCH*SEQ
#define KCH 64      // fused_attn k-chunk

typedef __bf16 bf16x8 __attribute__((ext_vector_type(8)));
typedef __bf16 bf16x4 __attribute__((ext_vector_type(4)));
typedef float f32x4 __attribute__((ext_vector_type(4)));

__device__ __forceinline__ void async_g2l_16(const void* g, void* l) {
  __builtin_amdgcn_global_load_lds(
      (const __attribute__((address_space(1))) unsigned int*)g,
      (__attribute__((address_space(3))) unsigned int*)l, 16, 0, 0);
}

// ---------------- fp32 -> bf16 hi/lo split (x) ----------------
__global__ __launch_bounds__(256) void cvt_split(const float* __restrict__ src,
                                                 __bf16* __restrict__ hi,
                                                 __bf16* __restrict__ lo, int n) {
  int i = (blockIdx.x * 256 + threadIdx.x) * 4;
  if (i < n) {
    float4 f = *(const float4*)(src + i);
    bf16x4 h, l;
    h[0] = (__bf16)f.x; l[0] = (__bf16)(f.x - (float)h[0]);
    h[1] = (__bf16)f.y; l[1] = (__bf16)(f.y - (float)h[1]);
    h[2] = (__bf16)f.z; l[2] = (__bf16)(f.z - (float)h[2]);
    h[3] = (__bf16)f.w; l[3] = (__bf16)(f.w - (float)h[3]);
    *(bf16x4*)(hi + i) = h;
    *(bf16x4*)(lo + i) = l;
  }
}

// ---------------- fp32 [R][C] -> bf16 transposed [C][R] ----------------
__global__ __launch_bounds__(256) void transpose_cvt_f32_bf16(
    const float* __restrict__ src, __bf16* __restrict__ dst, int R, int C) {
  __shared__ float t[32][33];
  const int rb = blockIdx.y * 32, cb = blockIdx.x * 32;
  const int c = threadIdx.x & 31;
  const int r0 = threadIdx.x >> 5;
#pragma unroll
  for (int rr = r0; rr < 32; rr += 8)
    t[rr][c] = src[(long)(rb + rr) * C + cb + c];
  __syncthreads();
#pragma unroll
  for (int rr = r0; rr < 32; rr += 8)
    dst[(long)(cb + rr) * R + rb + c] = (__bf16)t[c][rr];
}

// ---------------- CqkT (Bt layout [32][1024]) in bf16 hi/lo ----------------
// v2: float4 W reads (4x fewer W load instrs); We stays scalar (L1-hot 64KB).
__global__ __launch_bounds__(256) void k2_cqk(const float* __restrict__ Wq,
                                              const float* __restrict__ Wk,
                                              const float* __restrict__ We,
                                              __bf16* __restrict__ Cth,
                                              __bf16* __restrict__ Ctl) {
  const int gw = blockIdx.x * 4 + (threadIdx.x >> 6);  // 0..2047
  const int lane = threadIdx.x & 63;
  const int mat = gw & 1, k = gw >> 1;
  const float* Wrow = (mat ? Wk : Wq) + (long)k * H;
  const int col = lane & 15, q4 = lane >> 4;
  const float* wp = Wrow + q4 * 256;
  const float* wep = We + (long)q4 * 256 * QD + col;
  float acc = 0.f;
#pragma unroll 4
  for (int n0 = 0; n0 < 256; n0 += 4) {
    float4 w4 = *(const float4*)(wp + n0);
    acc += w4.x * wep[(n0 + 0) * QD];
    acc += w4.y * wep[(n0 + 1) * QD];
    acc += w4.z * wep[(n0 + 2) * QD];
    acc += w4.w * wep[(n0 + 3) * QD];
  }
  acc += __shfl_xor(acc, 16);
  acc += __shfl_xor(acc, 32);
  if (lane < 16) {
    __bf16 hi = (__bf16)acc;
    __bf16 lo = (__bf16)(acc - (float)hi);
    long idx = (long)(mat * 16 + col) * H + k;
    Cth[idx] = hi;
    Ctl[idx] = lo;
  }
}

// ---------------- dvec[j] = (bq|bk)@We + be (parallel v2) ----------------
__global__ __launch_bounds__(512) void k2b_dvec(
    const float* __restrict__ bq, const float* __restrict__ bk,
    const float* __restrict__ We, const float* __restrict__ be,
    float* __restrict__ dvec) {
  __shared__ float part[16][32];
  const int tid = threadIdx.x;  // 512
  const int j = tid & 31, p = tid >> 5;  // p 0..15
  const int mat = j >> 4, col = j & 15;
  const float* b = mat ? bk : bq;
  float acc = 0.f;
  for (int n = p * 64; n < p * 64 + 64; ++n) acc += b[n] * We[n * QD + col];
  part[p][j] = acc;
  __syncthreads();
  if (tid < 32) {
    float sum = be[tid & 15];
    for (int p2 = 0; p2 < 16; ++p2) sum += part[p2][tid];
    dvec[tid] = sum;
  }
}

// ---------------- embed via MFMA (hi/lo split), fused normalize ----------------
// v2: 1024 threads, 4-way K-split (each 256-thread group owns a K quarter),
// 4 staging rounds, 4 waves/SIMD. Partials combined via LDS at the end.
// Outputs bf16 qq/kk in [S][32] layout, zero-padded upper half; qq carries
// sqrt(log2 e).
__global__ __launch_bounds__(1024) void k3_embed_mfma(
    const __bf16* __restrict__ xh, const __bf16* __restrict__ xl,
    const __bf16* __restrict__ Cth, const __bf16* __restrict__ Ctl,
    const float* __restrict__ dvec, __bf16* __restrict__ qq32,
    __bf16* __restrict__ kk32) {
  __shared__ __bf16 Ah[4][32 * 64];
  __shared__ __bf16 Al[4][32 * 64];
  __shared__ __bf16 Bh[4][32 * 64];
  __shared__ __bf16 Bl[4][32 * 64];
  const int tid = threadIdx.x;
  const int lane = tid & 63;
  const int w = tid >> 6;       // 0..15
  const int kb = w >> 2;        // K quarter this wave computes on
  const int w4 = w & 3;
  const int rowhalf = w4 >> 1;  // 0/1 -> rows 0-15 / 16-31
  const int ntile = w4 & 1;     // 0 -> qq, 1 -> kk
  const int l15 = lane & 15, quad = lane >> 4;
  const long rowBase = (long)blockIdx.x * 32;

  const int half = tid >> 8;       // 0..3
  const int tl = tid & 255;
  const int srow = tl >> 3;        // 0..31
  const int seg = tl & 7;
  const int segsw = (seg ^ (srow & 7)) * 8;
  const long gk = half * 256 + segsw;
  const __bf16* agh = xh + (rowBase + srow) * H + gk;
  const __bf16* agl = xl + (rowBase + srow) * H + gk;
  const __bf16* bgh = Cth + (long)srow * H + gk;
  const __bf16* bgl = Ctl + (long)srow * H + gk;
  __bf16* lah = &Ah[half][srow * 64 + seg * 8];
  __bf16* lal = &Al[half][srow * 64 + seg * 8];
  __bf16* lbh = &Bh[half][srow * 64 + seg * 8];
  __bf16* lbl = &Bl[half][srow * 64 + seg * 8];

  f32x4 acc;
  acc[0] = 0.f; acc[1] = 0.f; acc[2] = 0.f; acc[3] = 0.f;
  const int arow = (rowhalf * 16 + l15) * 64;
  const int brow = (ntile * 16 + l15) * 64;
  const int h7 = l15 & 7;

  for (int k0 = 0; k0 < 256; k0 += 64) {
    async_g2l_16(agh + k0, lah);
    async_g2l_16(agl + k0, lal);
    async_g2l_16(bgh + k0, lbh);
    async_g2l_16(bgl + k0, lbl);
    __syncthreads();
#pragma unroll
    for (int s = 0; s < 2; ++s) {
      const int slot = ((s * 4 + quad) ^ h7) * 8;
      bf16x8 fah = *(const bf16x8*)&Ah[kb][arow + slot];
      bf16x8 fal = *(const bf16x8*)&Al[kb][arow + slot];
      bf16x8 fbh = *(const bf16x8*)&Bh[kb][brow + slot];
      bf16x8 fbl = *(const bf16x8*)&Bl[kb][brow + slot];
      acc = __builtin_amdgcn_mfma_f32_16x16x32_bf16(fah, fbh, acc, 0, 0, 0);
      acc = __builtin_amdgcn_mfma_f32_16x16x32_bf16(fal, fbh, acc, 0, 0, 0);
      acc = __builtin_amdgcn_mfma_f32_16x16x32_bf16(fah, fbl, acc, 0, 0, 0);
    }
    __syncthreads();
  }

  if (kb > 0) ((f32x4*)&Ah[kb][0])[w4 * 64 + lane] = acc;
  __syncthreads();
  if (kb == 0) {
#pragma unroll
    for (int q = 1; q < 4; ++q) {
      f32x4 o = ((const f32x4*)&Ah[q][0])[w4 * 64 + lane];
      acc[0] += o[0]; acc[1] += o[1]; acc[2] += o[2]; acc[3] += o[3];
    }
    const float dv = dvec[ntile * 16 + l15];
    const float osc = ntile ? 1.0f : 1.20112240878f;  // sqrt(log2 e) into qq
    __bf16* outp = ntile ? kk32 : qq32;
#pragma unroll
    for (int r = 0; r < 4; ++r) {
      float z = acc[r] + dv;
      float s2 = z * z;
      s2 += __shfl_xor(s2, 1);
      s2 += __shfl_xor(s2, 2);
      s2 += __shfl_xor(s2, 4);
      s2 += __shfl_xor(s2, 8);
      float val = z * rsqrtf(s2 + 1e-8f) * osc;
      long row = rowBase + rowhalf * 16 + quad * 4 + r;
      outp[row * 32 + l15] = (__bf16)val;
      outp[row * 32 + 16 + l15] = (__bf16)0.f;  // zero pad K 16->32
    }
  }
}

// ---------------- fused attention, 8 waves, 128q x 256h tile ----------------
// EXACT R6-benched structure (53.68us, best measured): KCH=64, V TRIPLE-
// buffered (3x32KB) via global_load_lds w/ pre-swizzled source, P DOUBLE-
// buffered (16B-granule XOR swizzle). ONE s_barrier per chunk, counted
// s_waitcnt vmcnt(6). XCD remap: 16 (b,h) panels -> 2/XCD, 1MB V panel
// L2-resident (FETCH 70->9MB verified R6). Buffer safety: stage(t)->buf
// (t+1)%3; PV(t) reads buf t%3; P halves alternate; fast waves blocked by
// barrier(t+1). NEW (T5): s_setprio(1) around the PV MFMA cluster — at
// 2 waves/SIMD one wave's S/exp2 overlaps the other's PV; priority biases
// the scheduler toward the MFMA-issuing wave.
__global__ __launch_bounds__(512) void fused_attn(
    const __bf16* __restrict__ qq32, const __bf16* __restrict__ kk32,
    const __bf16* __restrict__ v_t, __bf16* __restrict__ attn) {
  __shared__ __bf16 Vlds[3][256 * KCH];  // 96KB
  __shared__ __bf16 Plds[2][128 * KCH];  // 32KB
  __shared__ float rsum2[128 * 2];
  const int tid = threadIdx.x;
  const int lane = tid & 63;
  const int w = tid >> 6;  // 0..7
  const int l15 = lane & 15, quad = lane >> 4;
  const int ws_k = w & 1, ws_q = w >> 1;  // S-phase roles
  const int wp_h = w & 3, wp_q = w >> 2;  // PV-phase roles

  // XCD-aware remap: 256 blocks, 8 XCDs, 16 (b,h) panels -> 2 panels/XCD.
  const int bid = blockIdx.x;             // 0..255
  const int xcd = bid & 7, s = bid >> 3;  // s: 0..31
  const int panel = xcd * 2 + (s >> 4);   // 0..15
  const int b = panel >> 2;
  const long hbase = (long)(panel & 3) * 256;
  const long qbase = (long)(s & 15) * 128;

  // qq B-frags: 2, constant across the k-loop
  bf16x8 bq[2];
  {
    const __bf16* qqp =
        qq32 + ((long)b * SEQ + qbase + ws_q * 32 + l15) * 32 + quad * 8;
    bq[0] = *(const bf16x8*)qqp;
    bq[1] = *(const bf16x8*)(qqp + 16 * 32);
  }
  const __bf16* kkb = kk32 + ((long)b * SEQ + ws_k * 32 + l15) * 32 + quad * 8;

  // V staging: linear LDS dest (tid*16B), pre-swizzled global source.
  const int vR = tid >> 3;               // 0..63
  const int vSL = (tid & 7) ^ (vR & 7);  // swizzled global 16B-granule
  const __bf16* vgbase = v_t + (long)b * H * SEQ + (hbase + vR) * SEQ + vSL * 8;

  f32x4 acc[4][4];
#pragma unroll
  for (int i = 0; i < 4; ++i)
#pragma unroll
    for (int j = 0; j < 4; ++j) {
      acc[i][j][0] = 0.f; acc[i][j][1] = 0.f; acc[i][j][2] = 0.f; acc[i][j][3] = 0.f;
    }
  float rsPart[2] = {0.f, 0.f};

  // prologue: stage chunk 0 -> buf0 (4 vmem), load kk frags chunk 0 (2 vmem)
#pragma unroll
  for (int j = 0; j < 4; ++j)
    async_g2l_16(vgbase + (long)j * 64 * SEQ, &Vlds[0][j * 64 * KCH + tid * 8]);
  bf16x8 ak[2];
  ak[0] = *(const bf16x8*)kkb;
  ak[1] = *(const bf16x8*)(kkb + 16 * 32);

  int vcur = 0, vnxt = 1;
  for (int t = 0; t < SEQ / KCH; ++t) {
    const int kn = ((t + 1) & (SEQ / KCH - 1)) * KCH;  // wraps (dummy) at last
    // 1) issue stage of chunk t+1 (4 vmem ops)
#pragma unroll
    for (int j = 0; j < 4; ++j)
      async_g2l_16(vgbase + (long)j * 64 * SEQ + kn,
                   &Vlds[vnxt][j * 64 * KCH + tid * 8]);

    // 2) S-phase (chunk t): 4 MFMAs from regs -> exp2 -> Plds[t&1]
    __bf16* Pw = Plds[t & 1];
#pragma unroll
    for (int i = 0; i < 2; ++i) {
#pragma unroll
      for (int n = 0; n < 2; ++n) {
        f32x4 s2v;
        s2v[0] = 0.f; s2v[1] = 0.f; s2v[2] = 0.f; s2v[3] = 0.f;
        s2v = __builtin_amdgcn_mfma_f32_16x16x32_bf16(ak[i], bq[n], s2v, 0, 0, 0);
        bf16x4 pw;
        float part = 0.f;
#pragma unroll
        for (int r = 0; r < 4; ++r) {
          float wgt = exp2f(s2v[r] * s2v[r]);  // qq carries sqrt(log2e)
          part += wgt;
          pw[r] = (__bf16)wgt;
        }
        rsPart[n] += part;
        const int q = ws_q * 32 + n * 16 + l15;
        const int g = ws_k * 4 + i * 2 + (quad >> 1);
        *(bf16x4*)&Pw[q * KCH + ((g ^ (q & 7)) << 3) + (quad & 1) * 4] = pw;
      }
    }
    // 3) prefetch kk frags for chunk t+1 (2 vmem ops)
    ak[0] = *(const bf16x8*)(kkb + (long)kn * 32);
    ak[1] = *(const bf16x8*)(kkb + (long)(kn + 16) * 32);

    // 4) P writes visible; chunk-t V staged (6 younger vmem stay in flight)
    asm volatile("s_waitcnt lgkmcnt(0)" ::: "memory");
    asm volatile("s_waitcnt vmcnt(6)" ::: "memory");
    __builtin_amdgcn_sched_barrier(0);
    __builtin_amdgcn_s_barrier();

    // 5) PV: acc += P[128q x 64k] @ V[256h x 64k]^T   (wave: 64q x 64h)
    const __bf16* Vr = Vlds[vcur];
#pragma unroll
    for (int ks = 0; ks < 2; ++ks) {
      bf16x8 ap[4], bv[4];
#pragma unroll
      for (int i = 0; i < 4; ++i) {
        const int q = wp_q * 64 + i * 16 + l15;
        ap[i] = *(const bf16x8*)&Pw[q * KCH + (((ks * 4 + quad) ^ (q & 7)) << 3)];
      }
#pragma unroll
      for (int j = 0; j < 4; ++j) {
        const int vr = wp_h * 64 + j * 16 + l15;
        bv[j] = *(const bf16x8*)&Vr[vr * KCH + (((ks * 4 + quad) ^ (vr & 7)) << 3)];
      }
      __builtin_amdgcn_s_setprio(1);
#pragma unroll
      for (int i = 0; i < 4; ++i)
#pragma unroll
        for (int j = 0; j < 4; ++j)
          acc[i][j] =
              __builtin_amdgcn_mfma_f32_16x16x32_bf16(ap[i], bv[j], acc[i][j], 0, 0, 0);
      __builtin_amdgcn_s_setprio(0);
    }
    // 6) rotate V buffers (no second barrier needed: see header comment)
    const int third = 3 - vcur - vnxt;
    vcur = vnxt;
    vnxt = third;
  }

  // rowsum: reduce lane partials over quads, combine two k-halves via LDS
#pragma unroll
  for (int n = 0; n < 2; ++n) {
    float vs = rsPart[n];
    vs += __shfl_xor(vs, 16);
    vs += __shfl_xor(vs, 32);
    if (lane < 16) rsum2[(ws_q * 32 + n * 16 + l15) * 2 + ws_k] = vs;
  }
  __syncthreads();  // also drains the final dummy stage

  float rinv[4][4];
#pragma unroll
  for (int i = 0; i < 4; ++i)
#pragma unroll
    for (int r = 0; r < 4; ++r) {
      int row = wp_q * 64 + i * 16 + quad * 4 + r;
      rinv[i][r] = 1.0f / (rsum2[row * 2] + rsum2[row * 2 + 1]);
    }

  __bf16* ob = attn + ((long)b * SEQ + qbase) * H + hbase;
#pragma unroll
  for (int i = 0; i < 4; ++i)
#pragma unroll
    for (int j = 0; j < 4; ++j) {
      const int colL = wp_h * 64 + j * 16 + l15;
#pragma unroll
      for (int r = 0; r < 4; ++r) {
        const int rowL = wp_q * 64 + i * 16 + quad * 4 + r;
        ob[(long)rowL * H + colL] = (__bf16)(acc[i][j][r] * rinv[i][r]);
      }
    }
}

// ---------------- m97-style GEMM + XOR-swizzled LDS: C = A @ Bt^T (+bias) ----
// v2 (R7-benched): XCD-aware block remap (T1). Grid must be (8, 64): each XCD
// gets 8 contiguous row-panels x all 8 col-blocks -> each 256KB A-panel lives
// in exactly one XCD's L2.
// OUTMODE: 0 = fp32 row-major, 1 = bf16 row-major, 2 = bf16 transposed batched
//          (Cout layout [BATCH][N][SEQ], rows are per-batch: row = b*SEQ + rb)
template <int OUTMODE, int HASBIAS>
__global__ __launch_bounds__(256) void gemm_bt(
    const __bf16* __restrict__ A, const __bf16* __restrict__ Bt,
    void* __restrict__ Cout, const float* __restrict__ bias, int M, int N, int K) {
  __shared__ __bf16 Alds[128 * 64];
  __shared__ __bf16 Blds[128 * 64];
  const int tid = threadIdx.x;
  const int lane = tid & 63;
  const int w = tid >> 6;
  const int wm = w >> 1, wn = w & 1;
  const int l15 = lane & 15, quad = lane >> 4;

  // XCD remap (grid == (8,64), 512 blocks, round-robin dispatch):
  const int flat = blockIdx.y * 8 + blockIdx.x;  // 0..511
  const int xcd = flat & 7, idx = flat >> 3;     // idx 0..63
  const int rowPanel = xcd * 8 + (idx >> 3);     // 0..63
  const int colBlk = idx & 7;                    // 0..7
  const long rowBase = (long)rowPanel * 128;
  const long colBase = (long)colBlk * 128;

  const int srow = lane >> 3;                 // 0..7
  const int segsw = ((lane & 7) ^ srow) * 8;  // swizzled global k-seg

  const __bf16* ag[4];
  const __bf16* bg[4];
  __bf16* as_[4];
  __bf16* bs_[4];
#pragma unroll
  for (int j = 0; j < 4; ++j) {
    int r = j * 32 + w * 8;
    ag[j] = A + (rowBase + r + srow) * (long)K + segsw;
    bg[j] = Bt + (colBase + r + srow) * (long)K + segsw;
    as_[j] = &Alds[r * 64 + (lane & 7) * 8];
    bs_[j] = &Blds[r * 64 + (lane & 7) * 8];
  }

  f32x4 acc[4][4];
#pragma unroll
  for (int i = 0; i < 4; ++i)
#pragma unroll
    for (int j = 0; j < 4; ++j) {
      acc[i][j][0] = 0.f; acc[i][j][1] = 0.f; acc[i][j][2] = 0.f; acc[i][j][3] = 0.f;
    }

  const int h7 = l15 & 7;

  for (int k0 = 0; k0 < K; k0 += 64) {
#pragma unroll
    for (int j = 0; j < 4; ++j) {
      async_g2l_16(ag[j], as_[j]);
      async_g2l_16(bg[j], bs_[j]);
      ag[j] += 64;
      bg[j] += 64;
    }
    __syncthreads();
#pragma unroll
    for (int s = 0; s < 2; ++s) {
      const int slot = ((s * 4 + quad) ^ h7) * 8;
      bf16x8 af[4], bfv[4];
#pragma unroll
      for (int i = 0; i < 4; ++i) {
        af[i] = *(const bf16x8*)&Alds[(wm * 64 + i * 16 + l15) * 64 + slot];
        bfv[i] = *(const bf16x8*)&Blds[(wn * 64 + i * 16 + l15) * 64 + slot];
      }
#pragma unroll
      for (int i = 0; i < 4; ++i)
#pragma unroll
        for (int j = 0; j < 4; ++j)
          acc[i][j] =
              __builtin_amdgcn_mfma_f32_16x16x32_bf16(af[i], bfv[j], acc[i][j], 0, 0, 0);
    }
    __syncthreads();
  }

  const long crow0 = rowBase + wm * 64 + quad * 4;
  const long ccol0 = colBase + wn * 64 + l15;
#pragma unroll
  for (int i = 0; i < 4; ++i) {
#pragma unroll
    for (int j = 0; j < 4; ++j) {
      long col = ccol0 + j * 16;
      float bb = HASBIAS ? bias[col] : 0.f;
      if (OUTMODE == 2) {
        long row0 = crow0 + i * 16;          // 4 consecutive rows, same batch
        int bz = (int)(row0 >> 11);          // row / SEQ
        long rb = row0 & (SEQ - 1);
        bf16x4 pv;
#pragma unroll
        for (int r = 0; r < 4; ++r) pv[r] = (__bf16)(acc[i][j][r] + bb);
        *(bf16x4*)&((__bf16*)Cout)[((long)bz * N + col) * SEQ + rb] = pv;
      } else {
#pragma unroll
        for (int r = 0; r < 4; ++r) {
          long row = crow0 + i * 16 + r;
          float val = acc[i][j][r] + bb;
          if (OUTMODE == 0)
            ((float*)Cout)[row * N + col] = val;
          else
            ((__bf16*)Cout)[row * N + col] = (__bf16)val;
        }
      }
    }
  }
}

extern "C" void kernel_launch(void* const* d_in, const int* in_sizes, int n_in,
                              void* d_out, int out_size, void* d_ws, size_t ws_size,
                              hipStream_t stream) {
  const float* x = (const float*)d_in[0];
  const float* Wq = (const float*)d_in[1];
  const float* bq = (const float*)d_in[2];
  const float* Wk = (const float*)d_in[3];
  const float* bk = (const float*)d_in[4];
  const float* Wv = (const float*)d_in[5];
  const float* bv = (const float*)d_in[6];
  const float* We = (const float*)d_in[7];
  const float* be = (const float*)d_in[8];
  const float* Wo = (const float*)d_in[9];
  const float* bo = (const float*)d_in[10];
  float* out = (float*)d_out;

  char* ws = (char*)d_ws;
  size_t o = 0;
  auto alloc = [&](size_t n) {
    size_t r = o;
    o += (n + 255) & ~(size_t)255;
    return r;
  };
  __bf16* xbf = (__bf16*)(ws + alloc((size_t)MROWS * H * 2));  // x hi
  __bf16* v_t = (__bf16*)(ws + alloc((size_t)MROWS * H * 2));  // v^T [B][H][S]
  __bf16* attn = (__bf16*)(ws + alloc((size_t)MROWS * H * 2));
  __bf16* Wvt = (__bf16*)(ws + alloc((size_t)H * H * 2));
  __bf16* Wot = (__bf16*)(ws + alloc((size_t)H * H * 2));
  __bf16* Cth = (__bf16*)(ws + alloc((size_t)32 * H * 2));
  __bf16* Ctl = (__bf16*)(ws + alloc((size_t)32 * H * 2));
  float* dvec = (float*)(ws + alloc(32 * 4));
  __bf16* qq32 = (__bf16*)(ws + alloc((size_t)MROWS * 32 * 2));
  __bf16* kk32 = (__bf16*)(ws + alloc((size_t)MROWS * 32 * 2));
  // Alias (stream-ordered lifetime separation):
  __bf16* xlo = attn;  // x lo part: dead before attn is written (fused_attn)
  if (ws_size < o) return;

  // 1) x -> bf16 hi/lo split
  cvt_split<<<MROWS * H / 1024, 256, 0, stream>>>(x, xbf, xlo, MROWS * H);
  // 2) Wv^T, Wo^T as bf16
  transpose_cvt_f32_bf16<<<dim3(32, 32), 256, 0, stream>>>(Wv, Wvt, H, H);
  transpose_cvt_f32_bf16<<<dim3(32, 32), 256, 0, stream>>>(Wo, Wot, H, H);
  // 3) collapsed embed matrices (bf16 hi/lo, Bt layout) + bias fold
  k2_cqk<<<512, 256, 0, stream>>>(Wq, Wk, We, Cth, Ctl);
  k2b_dvec<<<1, 512, 0, stream>>>(bq, bk, We, be, dvec);
  // 4) unit-norm quantum embeds via MFMA (4-way K-split, 16 waves)
  k3_embed_mfma<<<MROWS / 32, 1024, 0, stream>>>(xbf, xlo, Cth, Ctl, dvec, qq32, kk32);
  // 5) v = x@Wv + bv, written TRANSPOSED per batch -> v_t[b][h][s]
  gemm_bt<2, 1><<<dim3(8, 64), 256, 0, stream>>>(xbf, Wvt, v_t, bv, MROWS, H, H);
  // 6) fused: S^T once per 256h -> exp2(S'^2) -> P@v/rowsum (8 waves, setprio)
  fused_attn<<<256, 512, 0, stream>>>(qq32, kk32, v_t, attn);
  // 7) out = attended @ Wo + bo  (fp32 out)
  gemm_bt<0, 1><<<dim3(8, 64), 256, 0, stream>>>(attn, Wot, out, bo, MROWS, H, H);
}

// Round 11
// 238.726 us; speedup vs baseline: 1.0804x; 1.0059x over previous
//
#include <hip/hip_runtime.h>

#define H 1024
#define QD 16
#define BATCH 4
#define SEQ 2048
#define MROWS 8192  // BATCH*SEQ
#define KCH 64      // fused_attn k-chunk

typedef __bf16 bf16x8 __attribute__((ext_vector_type(8)));
typedef __bf16 bf16x4 __attribute__((ext_vector_type(4)));
typedef float f32x4 __attribute__((ext_vector_type(4)));

__device__ __forceinline__ void async_g2l_16(const void* g, void* l) {
  __builtin_amdgcn_global_load_lds(
      (const __attribute__((address_space(1))) unsigned int*)g,
      (__attribute__((address_space(3))) unsigned int*)l, 16, 0, 0);
}

// ---------------- fp32 -> bf16 hi/lo split (x) ----------------
__global__ __launch_bounds__(256) void cvt_split(const float* __restrict__ src,
                                                 __bf16* __restrict__ hi,
                                                 __bf16* __restrict__ lo, int n) {
  int i = (blockIdx.x * 256 + threadIdx.x) * 4;
  if (i < n) {
    float4 f = *(const float4*)(src + i);
    bf16x4 h, l;
    h[0] = (__bf16)f.x; l[0] = (__bf16)(f.x - (float)h[0]);
    h[1] = (__bf16)f.y; l[1] = (__bf16)(f.y - (float)h[1]);
    h[2] = (__bf16)f.z; l[2] = (__bf16)(f.z - (float)h[2]);
    h[3] = (__bf16)f.w; l[3] = (__bf16)(f.w - (float)h[3]);
    *(bf16x4*)(hi + i) = h;
    *(bf16x4*)(lo + i) = l;
  }
}

// ---------------- fp32 [R][C] -> bf16 transposed [C][R] ----------------
__global__ __launch_bounds__(256) void transpose_cvt_f32_bf16(
    const float* __restrict__ src, __bf16* __restrict__ dst, int R, int C) {
  __shared__ float t[32][33];
  const int rb = blockIdx.y * 32, cb = blockIdx.x * 32;
  const int c = threadIdx.x & 31;
  const int r0 = threadIdx.x >> 5;
#pragma unroll
  for (int rr = r0; rr < 32; rr += 8)
    t[rr][c] = src[(long)(rb + rr) * C + cb + c];
  __syncthreads();
#pragma unroll
  for (int rr = r0; rr < 32; rr += 8)
    dst[(long)(cb + rr) * R + rb + c] = (__bf16)t[c][rr];
}

// ---------------- CqkT (Bt layout [32][1024]) in bf16 hi/lo ----------------
// v2: float4 W reads (4x fewer W load instrs); We stays scalar (L1-hot 64KB).
__global__ __launch_bounds__(256) void k2_cqk(const float* __restrict__ Wq,
                                              const float* __restrict__ Wk,
                                              const float* __restrict__ We,
                                              __bf16* __restrict__ Cth,
                                              __bf16* __restrict__ Ctl) {
  const int gw = blockIdx.x * 4 + (threadIdx.x >> 6);  // 0..2047
  const int lane = threadIdx.x & 63;
  const int mat = gw & 1, k = gw >> 1;
  const float* Wrow = (mat ? Wk : Wq) + (long)k * H;
  const int col = lane & 15, q4 = lane >> 4;
  const float* wp = Wrow + q4 * 256;
  const float* wep = We + (long)q4 * 256 * QD + col;
  float acc = 0.f;
#pragma unroll 4
  for (int n0 = 0; n0 < 256; n0 += 4) {
    float4 w4 = *(const float4*)(wp + n0);
    acc += w4.x * wep[(n0 + 0) * QD];
    acc += w4.y * wep[(n0 + 1) * QD];
    acc += w4.z * wep[(n0 + 2) * QD];
    acc += w4.w * wep[(n0 + 3) * QD];
  }
  acc += __shfl_xor(acc, 16);
  acc += __shfl_xor(acc, 32);
  if (lane < 16) {
    __bf16 hi = (__bf16)acc;
    __bf16 lo = (__bf16)(acc - (float)hi);
    long idx = (long)(mat * 16 + col) * H + k;
    Cth[idx] = hi;
    Ctl[idx] = lo;
  }
}

// ---------------- dvec[j] = (bq|bk)@We + be (parallel v2) ----------------
__global__ __launch_bounds__(512) void k2b_dvec(
    const float* __restrict__ bq, const float* __restrict__ bk,
    const float* __restrict__ We, const float* __restrict__ be,
    float* __restrict__ dvec) {
  __shared__ float part[16][32];
  const int tid = threadIdx.x;  // 512
  const int j = tid & 31, p = tid >> 5;  // p 0..15
  const int mat = j >> 4, col = j & 15;
  const float* b = mat ? bk : bq;
  float acc = 0.f;
  for (int n = p * 64; n < p * 64 + 64; ++n) acc += b[n] * We[n * QD + col];
  part[p][j] = acc;
  __syncthreads();
  if (tid < 32) {
    float sum = be[tid & 15];
    for (int p2 = 0; p2 < 16; ++p2) sum += part[p2][tid];
    dvec[tid] = sum;
  }
}

// ---------------- embed via MFMA (hi/lo split), fused normalize ----------------
// v2: 1024 threads, 4-way K-split (each 256-thread group owns a K quarter),
// 4 staging rounds, 4 waves/SIMD. Partials combined via LDS at the end.
// Outputs bf16 qq/kk in [S][32] layout, zero-padded upper half; qq carries
// sqrt(log2 e).
__global__ __launch_bounds__(1024) void k3_embed_mfma(
    const __bf16* __restrict__ xh, const __bf16* __restrict__ xl,
    const __bf16* __restrict__ Cth, const __bf16* __restrict__ Ctl,
    const float* __restrict__ dvec, __bf16* __restrict__ qq32,
    __bf16* __restrict__ kk32) {
  __shared__ __bf16 Ah[4][32 * 64];
  __shared__ __bf16 Al[4][32 * 64];
  __shared__ __bf16 Bh[4][32 * 64];
  __shared__ __bf16 Bl[4][32 * 64];
  const int tid = threadIdx.x;
  const int lane = tid & 63;
  const int w = tid >> 6;       // 0..15
  const int kb = w >> 2;        // K quarter this wave computes on
  const int w4 = w & 3;
  const int rowhalf = w4 >> 1;  // 0/1 -> rows 0-15 / 16-31
  const int ntile = w4 & 1;     // 0 -> qq, 1 -> kk
  const int l15 = lane & 15, quad = lane >> 4;
  const long rowBase = (long)blockIdx.x * 32;

  const int half = tid >> 8;       // 0..3
  const int tl = tid & 255;
  const int srow = tl >> 3;        // 0..31
  const int seg = tl & 7;
  const int segsw = (seg ^ (srow & 7)) * 8;
  const long gk = half * 256 + segsw;
  const __bf16* agh = xh + (rowBase + srow) * H + gk;
  const __bf16* agl = xl + (rowBase + srow) * H + gk;
  const __bf16* bgh = Cth + (long)srow * H + gk;
  const __bf16* bgl = Ctl + (long)srow * H + gk;
  __bf16* lah = &Ah[half][srow * 64 + seg * 8];
  __bf16* lal = &Al[half][srow * 64 + seg * 8];
  __bf16* lbh = &Bh[half][srow * 64 + seg * 8];
  __bf16* lbl = &Bl[half][srow * 64 + seg * 8];

  f32x4 acc;
  acc[0] = 0.f; acc[1] = 0.f; acc[2] = 0.f; acc[3] = 0.f;
  const int arow = (rowhalf * 16 + l15) * 64;
  const int brow = (ntile * 16 + l15) * 64;
  const int h7 = l15 & 7;

  for (int k0 = 0; k0 < 256; k0 += 64) {
    async_g2l_16(agh + k0, lah);
    async_g2l_16(agl + k0, lal);
    async_g2l_16(bgh + k0, lbh);
    async_g2l_16(bgl + k0, lbl);
    __syncthreads();
#pragma unroll
    for (int s = 0; s < 2; ++s) {
      const int slot = ((s * 4 + quad) ^ h7) * 8;
      bf16x8 fah = *(const bf16x8*)&Ah[kb][arow + slot];
      bf16x8 fal = *(const bf16x8*)&Al[kb][arow + slot];
      bf16x8 fbh = *(const bf16x8*)&Bh[kb][brow + slot];
      bf16x8 fbl = *(const bf16x8*)&Bl[kb][brow + slot];
      acc = __builtin_amdgcn_mfma_f32_16x16x32_bf16(fah, fbh, acc, 0, 0, 0);
      acc = __builtin_amdgcn_mfma_f32_16x16x32_bf16(fal, fbh, acc, 0, 0, 0);
      acc = __builtin_amdgcn_mfma_f32_16x16x32_bf16(fah, fbl, acc, 0, 0, 0);
    }
    __syncthreads();
  }

  if (kb > 0) ((f32x4*)&Ah[kb][0])[w4 * 64 + lane] = acc;
  __syncthreads();
  if (kb == 0) {
#pragma unroll
    for (int q = 1; q < 4; ++q) {
      f32x4 o = ((const f32x4*)&Ah[q][0])[w4 * 64 + lane];
      acc[0] += o[0]; acc[1] += o[1]; acc[2] += o[2]; acc[3] += o[3];
    }
    const float dv = dvec[ntile * 16 + l15];
    const float osc = ntile ? 1.0f : 1.20112240878f;  // sqrt(log2 e) into qq
    __bf16* outp = ntile ? kk32 : qq32;
#pragma unroll
    for (int r = 0; r < 4; ++r) {
      float z = acc[r] + dv;
      float s2 = z * z;
      s2 += __shfl_xor(s2, 1);
      s2 += __shfl_xor(s2, 2);
      s2 += __shfl_xor(s2, 4);
      s2 += __shfl_xor(s2, 8);
      float val = z * rsqrtf(s2 + 1e-8f) * osc;
      long row = rowBase + rowhalf * 16 + quad * 4 + r;
      outp[row * 32 + l15] = (__bf16)val;
      outp[row * 32 + 16 + l15] = (__bf16)0.f;  // zero pad K 16->32
    }
  }
}

// ---------------- fused attention, 8 waves, 128q x 256h tile ----------------
// EXACT R6-benched structure (53.68us, best measured — setprio removed after
// R10 measured it at +6.3us, consistent with T5's m190 GEMM null/regression):
// KCH=64, V TRIPLE-buffered (3x32KB) via global_load_lds w/ pre-swizzled
// source, P DOUBLE-buffered (16B-granule XOR swizzle). ONE s_barrier per
// chunk, counted s_waitcnt vmcnt(6). XCD remap: 16 (b,h) panels -> 2/XCD,
// 1MB V panel L2-resident (FETCH 70->9MB verified R6). Buffer safety:
// stage(t)->buf (t+1)%3; PV(t) reads buf t%3; P halves alternate; fast waves
// blocked by barrier(t+1).
__global__ __launch_bounds__(512) void fused_attn(
    const __bf16* __restrict__ qq32, const __bf16* __restrict__ kk32,
    const __bf16* __restrict__ v_t, __bf16* __restrict__ attn) {
  __shared__ __bf16 Vlds[3][256 * KCH];  // 96KB
  __shared__ __bf16 Plds[2][128 * KCH];  // 32KB
  __shared__ float rsum2[128 * 2];
  const int tid = threadIdx.x;
  const int lane = tid & 63;
  const int w = tid >> 6;  // 0..7
  const int l15 = lane & 15, quad = lane >> 4;
  const int ws_k = w & 1, ws_q = w >> 1;  // S-phase roles
  const int wp_h = w & 3, wp_q = w >> 2;  // PV-phase roles

  // XCD-aware remap: 256 blocks, 8 XCDs, 16 (b,h) panels -> 2 panels/XCD.
  const int bid = blockIdx.x;             // 0..255
  const int xcd = bid & 7, s = bid >> 3;  // s: 0..31
  const int panel = xcd * 2 + (s >> 4);   // 0..15
  const int b = panel >> 2;
  const long hbase = (long)(panel & 3) * 256;
  const long qbase = (long)(s & 15) * 128;

  // qq B-frags: 2, constant across the k-loop
  bf16x8 bq[2];
  {
    const __bf16* qqp =
        qq32 + ((long)b * SEQ + qbase + ws_q * 32 + l15) * 32 + quad * 8;
    bq[0] = *(const bf16x8*)qqp;
    bq[1] = *(const bf16x8*)(qqp + 16 * 32);
  }
  const __bf16* kkb = kk32 + ((long)b * SEQ + ws_k * 32 + l15) * 32 + quad * 8;

  // V staging: linear LDS dest (tid*16B), pre-swizzled global source.
  const int vR = tid >> 3;               // 0..63
  const int vSL = (tid & 7) ^ (vR & 7);  // swizzled global 16B-granule
  const __bf16* vgbase = v_t + (long)b * H * SEQ + (hbase + vR) * SEQ + vSL * 8;

  f32x4 acc[4][4];
#pragma unroll
  for (int i = 0; i < 4; ++i)
#pragma unroll
    for (int j = 0; j < 4; ++j) {
      acc[i][j][0] = 0.f; acc[i][j][1] = 0.f; acc[i][j][2] = 0.f; acc[i][j][3] = 0.f;
    }
  float rsPart[2] = {0.f, 0.f};

  // prologue: stage chunk 0 -> buf0 (4 vmem), load kk frags chunk 0 (2 vmem)
#pragma unroll
  for (int j = 0; j < 4; ++j)
    async_g2l_16(vgbase + (long)j * 64 * SEQ, &Vlds[0][j * 64 * KCH + tid * 8]);
  bf16x8 ak[2];
  ak[0] = *(const bf16x8*)kkb;
  ak[1] = *(const bf16x8*)(kkb + 16 * 32);

  int vcur = 0, vnxt = 1;
  for (int t = 0; t < SEQ / KCH; ++t) {
    const int kn = ((t + 1) & (SEQ / KCH - 1)) * KCH;  // wraps (dummy) at last
    // 1) issue stage of chunk t+1 (4 vmem ops)
#pragma unroll
    for (int j = 0; j < 4; ++j)
      async_g2l_16(vgbase + (long)j * 64 * SEQ + kn,
                   &Vlds[vnxt][j * 64 * KCH + tid * 8]);

    // 2) S-phase (chunk t): 4 MFMAs from regs -> exp2 -> Plds[t&1]
    __bf16* Pw = Plds[t & 1];
#pragma unroll
    for (int i = 0; i < 2; ++i) {
#pragma unroll
      for (int n = 0; n < 2; ++n) {
        f32x4 s2v;
        s2v[0] = 0.f; s2v[1] = 0.f; s2v[2] = 0.f; s2v[3] = 0.f;
        s2v = __builtin_amdgcn_mfma_f32_16x16x32_bf16(ak[i], bq[n], s2v, 0, 0, 0);
        bf16x4 pw;
        float part = 0.f;
#pragma unroll
        for (int r = 0; r < 4; ++r) {
          float wgt = exp2f(s2v[r] * s2v[r]);  // qq carries sqrt(log2e)
          part += wgt;
          pw[r] = (__bf16)wgt;
        }
        rsPart[n] += part;
        const int q = ws_q * 32 + n * 16 + l15;
        const int g = ws_k * 4 + i * 2 + (quad >> 1);
        *(bf16x4*)&Pw[q * KCH + ((g ^ (q & 7)) << 3) + (quad & 1) * 4] = pw;
      }
    }
    // 3) prefetch kk frags for chunk t+1 (2 vmem ops)
    ak[0] = *(const bf16x8*)(kkb + (long)kn * 32);
    ak[1] = *(const bf16x8*)(kkb + (long)(kn + 16) * 32);

    // 4) P writes visible; chunk-t V staged (6 younger vmem stay in flight)
    asm volatile("s_waitcnt lgkmcnt(0)" ::: "memory");
    asm volatile("s_waitcnt vmcnt(6)" ::: "memory");
    __builtin_amdgcn_sched_barrier(0);
    __builtin_amdgcn_s_barrier();

    // 5) PV: acc += P[128q x 64k] @ V[256h x 64k]^T   (wave: 64q x 64h)
    const __bf16* Vr = Vlds[vcur];
#pragma unroll
    for (int ks = 0; ks < 2; ++ks) {
      bf16x8 ap[4], bv[4];
#pragma unroll
      for (int i = 0; i < 4; ++i) {
        const int q = wp_q * 64 + i * 16 + l15;
        ap[i] = *(const bf16x8*)&Pw[q * KCH + (((ks * 4 + quad) ^ (q & 7)) << 3)];
      }
#pragma unroll
      for (int j = 0; j < 4; ++j) {
        const int vr = wp_h * 64 + j * 16 + l15;
        bv[j] = *(const bf16x8*)&Vr[vr * KCH + (((ks * 4 + quad) ^ (vr & 7)) << 3)];
      }
#pragma unroll
      for (int i = 0; i < 4; ++i)
#pragma unroll
        for (int j = 0; j < 4; ++j)
          acc[i][j] =
              __builtin_amdgcn_mfma_f32_16x16x32_bf16(ap[i], bv[j], acc[i][j], 0, 0, 0);
    }
    // 6) rotate V buffers (no second barrier needed: see header comment)
    const int third = 3 - vcur - vnxt;
    vcur = vnxt;
    vnxt = third;
  }

  // rowsum: reduce lane partials over quads, combine two k-halves via LDS
#pragma unroll
  for (int n = 0; n < 2; ++n) {
    float vs = rsPart[n];
    vs += __shfl_xor(vs, 16);
    vs += __shfl_xor(vs, 32);
    if (lane < 16) rsum2[(ws_q * 32 + n * 16 + l15) * 2 + ws_k] = vs;
  }
  __syncthreads();  // also drains the final dummy stage

  float rinv[4][4];
#pragma unroll
  for (int i = 0; i < 4; ++i)
#pragma unroll
    for (int r = 0; r < 4; ++r) {
      int row = wp_q * 64 + i * 16 + quad * 4 + r;
      rinv[i][r] = 1.0f / (rsum2[row * 2] + rsum2[row * 2 + 1]);
    }

  __bf16* ob = attn + ((long)b * SEQ + qbase) * H + hbase;
#pragma unroll
  for (int i = 0; i < 4; ++i)
#pragma unroll
    for (int j = 0; j < 4; ++j) {
      const int colL = wp_h * 64 + j * 16 + l15;
#pragma unroll
      for (int r = 0; r < 4; ++r) {
        const int rowL = wp_q * 64 + i * 16 + quad * 4 + r;
        ob[(long)rowL * H + colL] = (__bf16)(acc[i][j][r] * rinv[i][r]);
      }
    }
}

// ---------------- m97-style GEMM + XOR-swizzled LDS: C = A @ Bt^T (+bias) ----
// v2 (R7-benched): XCD-aware block remap (T1). Grid must be (8, 64): each XCD
// gets 8 contiguous row-panels x all 8 col-blocks -> each 256KB A-panel lives
// in exactly one XCD's L2.
// OUTMODE: 0 = fp32 row-major, 1 = bf16 row-major, 2 = bf16 transposed batched
//          (Cout layout [BATCH][N][SEQ], rows are per-batch: row = b*SEQ + rb)
template <int OUTMODE, int HASBIAS>
__global__ __launch_bounds__(256) void gemm_bt(
    const __bf16* __restrict__ A, const __bf16* __restrict__ Bt,
    void* __restrict__ Cout, const float* __restrict__ bias, int M, int N, int K) {
  __shared__ __bf16 Alds[128 * 64];
  __shared__ __bf16 Blds[128 * 64];
  const int tid = threadIdx.x;
  const int lane = tid & 63;
  const int w = tid >> 6;
  const int wm = w >> 1, wn = w & 1;
  const int l15 = lane & 15, quad = lane >> 4;

  // XCD remap (grid == (8,64), 512 blocks, round-robin dispatch):
  const int flat = blockIdx.y * 8 + blockIdx.x;  // 0..511
  const int xcd = flat & 7, idx = flat >> 3;     // idx 0..63
  const int rowPanel = xcd * 8 + (idx >> 3);     // 0..63
  const int colBlk = idx & 7;                    // 0..7
  const long rowBase = (long)rowPanel * 128;
  const long colBase = (long)colBlk * 128;

  const int srow = lane >> 3;                 // 0..7
  const int segsw = ((lane & 7) ^ srow) * 8;  // swizzled global k-seg

  const __bf16* ag[4];
  const __bf16* bg[4];
  __bf16* as_[4];
  __bf16* bs_[4];
#pragma unroll
  for (int j = 0; j < 4; ++j) {
    int r = j * 32 + w * 8;
    ag[j] = A + (rowBase + r + srow) * (long)K + segsw;
    bg[j] = Bt + (colBase + r + srow) * (long)K + segsw;
    as_[j] = &Alds[r * 64 + (lane & 7) * 8];
    bs_[j] = &Blds[r * 64 + (lane & 7) * 8];
  }

  f32x4 acc[4][4];
#pragma unroll
  for (int i = 0; i < 4; ++i)
#pragma unroll
    for (int j = 0; j < 4; ++j) {
      acc[i][j][0] = 0.f; acc[i][j][1] = 0.f; acc[i][j][2] = 0.f; acc[i][j][3] = 0.f;
    }

  const int h7 = l15 & 7;

  for (int k0 = 0; k0 < K; k0 += 64) {
#pragma unroll
    for (int j = 0; j < 4; ++j) {
      async_g2l_16(ag[j], as_[j]);
      async_g2l_16(bg[j], bs_[j]);
      ag[j] += 64;
      bg[j] += 64;
    }
    __syncthreads();
#pragma unroll
    for (int s = 0; s < 2; ++s) {
      const int slot = ((s * 4 + quad) ^ h7) * 8;
      bf16x8 af[4], bfv[4];
#pragma unroll
      for (int i = 0; i < 4; ++i) {
        af[i] = *(const bf16x8*)&Alds[(wm * 64 + i * 16 + l15) * 64 + slot];
        bfv[i] = *(const bf16x8*)&Blds[(wn * 64 + i * 16 + l15) * 64 + slot];
      }
#pragma unroll
      for (int i = 0; i < 4; ++i)
#pragma unroll
        for (int j = 0; j < 4; ++j)
          acc[i][j] =
              __builtin_amdgcn_mfma_f32_16x16x32_bf16(af[i], bfv[j], acc[i][j], 0, 0, 0);
    }
    __syncthreads();
  }

  const long crow0 = rowBase + wm * 64 + quad * 4;
  const long ccol0 = colBase + wn * 64 + l15;
#pragma unroll
  for (int i = 0; i < 4; ++i) {
#pragma unroll
    for (int j = 0; j < 4; ++j) {
      long col = ccol0 + j * 16;
      float bb = HASBIAS ? bias[col] : 0.f;
      if (OUTMODE == 2) {
        long row0 = crow0 + i * 16;          // 4 consecutive rows, same batch
        int bz = (int)(row0 >> 11);          // row / SEQ
        long rb = row0 & (SEQ - 1);
        bf16x4 pv;
#pragma unroll
        for (int r = 0; r < 4; ++r) pv[r] = (__bf16)(acc[i][j][r] + bb);
        *(bf16x4*)&((__bf16*)Cout)[((long)bz * N + col) * SEQ + rb] = pv;
      } else {
#pragma unroll
        for (int r = 0; r < 4; ++r) {
          long row = crow0 + i * 16 + r;
          float val = acc[i][j][r] + bb;
          if (OUTMODE == 0)
            ((float*)Cout)[row * N + col] = val;
          else
            ((__bf16*)Cout)[row * N + col] = (__bf16)val;
        }
      }
    }
  }
}

extern "C" void kernel_launch(void* const* d_in, const int* in_sizes, int n_in,
                              void* d_out, int out_size, void* d_ws, size_t ws_size,
                              hipStream_t stream) {
  const float* x = (const float*)d_in[0];
  const float* Wq = (const float*)d_in[1];
  const float* bq = (const float*)d_in[2];
  const float* Wk = (const float*)d_in[3];
  const float* bk = (const float*)d_in[4];
  const float* Wv = (const float*)d_in[5];
  const float* bv = (const float*)d_in[6];
  const float* We = (const float*)d_in[7];
  const float* be = (const float*)d_in[8];
  const float* Wo = (const float*)d_in[9];
  const float* bo = (const float*)d_in[10];
  float* out = (float*)d_out;

  char* ws = (char*)d_ws;
  size_t o = 0;
  auto alloc = [&](size_t n) {
    size_t r = o;
    o += (n + 255) & ~(size_t)255;
    return r;
  };
  __bf16* xbf = (__bf16*)(ws + alloc((size_t)MROWS * H * 2));  // x hi
  __bf16* v_t = (__bf16*)(ws + alloc((size_t)MROWS * H * 2));  // v^T [B][H][S]
  __bf16* attn = (__bf16*)(ws + alloc((size_t)MROWS * H * 2));
  __bf16* Wvt = (__bf16*)(ws + alloc((size_t)H * H * 2));
  __bf16* Wot = (__bf16*)(ws + alloc((size_t)H * H * 2));
  __bf16* Cth = (__bf16*)(ws + alloc((size_t)32 * H * 2));
  __bf16* Ctl = (__bf16*)(ws + alloc((size_t)32 * H * 2));
  float* dvec = (float*)(ws + alloc(32 * 4));
  __bf16* qq32 = (__bf16*)(ws + alloc((size_t)MROWS * 32 * 2));
  __bf16* kk32 = (__bf16*)(ws + alloc((size_t)MROWS * 32 * 2));
  // Alias (stream-ordered lifetime separation):
  __bf16* xlo = attn;  // x lo part: dead before attn is written (fused_attn)
  if (ws_size < o) return;

  // 1) x -> bf16 hi/lo split
  cvt_split<<<MROWS * H / 1024, 256, 0, stream>>>(x, xbf, xlo, MROWS * H);
  // 2) Wv^T, Wo^T as bf16
  transpose_cvt_f32_bf16<<<dim3(32, 32), 256, 0, stream>>>(Wv, Wvt, H, H);
  transpose_cvt_f32_bf16<<<dim3(32, 32), 256, 0, stream>>>(Wo, Wot, H, H);
  // 3) collapsed embed matrices (bf16 hi/lo, Bt layout) + bias fold
  k2_cqk<<<512, 256, 0, stream>>>(Wq, Wk, We, Cth, Ctl);
  k2b_dvec<<<1, 512, 0, stream>>>(bq, bk, We, be, dvec);
  // 4) unit-norm quantum embeds via MFMA (4-way K-split, 16 waves)
  k3_embed_mfma<<<MROWS / 32, 1024, 0, stream>>>(xbf, xlo, Cth, Ctl, dvec, qq32, kk32);
  // 5) v = x@Wv + bv, written TRANSPOSED per batch -> v_t[b][h][s]
  gemm_bt<2, 1><<<dim3(8, 64), 256, 0, stream>>>(xbf, Wvt, v_t, bv, MROWS, H, H);
  // 6) fused: S^T once per 256h -> exp2(S'^2) -> P@v/rowsum (8 waves)
  fused_attn<<<256, 512, 0, stream>>>(qq32, kk32, v_t, attn);
  // 7) out = attended @ Wo + bo  (fp32 out)
  gemm_bt<0, 1><<<dim3(8, 64), 256, 0, stream>>>(attn, Wot, out, bo, MROWS, H, H);
}